// Round 2
// baseline (387.549 us; speedup 1.0000x reference)
//
#include <hip/hip_runtime.h>
#include <hip/hip_fp16.h>

#define S_TOK 8192
#define DDIM  1024
#define HDIM  4096
#define NEXP  8
#define CAP   1024

typedef __attribute__((ext_vector_type(8))) _Float16 half8;
typedef __attribute__((ext_vector_type(2))) _Float16 half2v;
typedef __attribute__((ext_vector_type(4))) float f32x4;

__device__ __forceinline__ void load_lds16(const _Float16* g, _Float16* l) {
  __builtin_amdgcn_global_load_lds(
      (const __attribute__((address_space(1))) unsigned int*)g,
      (__attribute__((address_space(3))) unsigned int*)l, 16, 0, 0);
}

// LDS fragment address with the same XOR swizzle used on the staging source.
// Tile stored as two 64-row halves of [64 rows][32 halfs]; chunk col c (16B)
// of row r holds global k-chunk (c ^ ((r>>1)&3)).
__device__ __forceinline__ int lds_idx(int r, int kslot) {
  return (r & 63) * 32 + (r >> 6) * 2048 + ((kslot ^ ((r >> 1) & 3)) << 3);
}

// ---------------- gating: logits = x @ wg, softmax, top-1 ----------------
__global__ __launch_bounds__(256) void moe_gating(const float* __restrict__ x,
                                                  const float* __restrict__ wg,
                                                  int* __restrict__ eidx,
                                                  float* __restrict__ gtok) {
  const int s = blockIdx.x * 4 + (threadIdx.x >> 6);
  const int lane = threadIdx.x & 63;
  const float* xr = x + (size_t)s * DDIM;
  float acc[NEXP];
#pragma unroll
  for (int e = 0; e < NEXP; ++e) acc[e] = 0.f;
  for (int d = lane; d < DDIM; d += 64) {
    float xv = xr[d];
    const float4* wrow = (const float4*)(wg + (size_t)d * NEXP);
    float4 w0 = wrow[0], w1v = wrow[1];
    acc[0] += xv * w0.x;  acc[1] += xv * w0.y;
    acc[2] += xv * w0.z;  acc[3] += xv * w0.w;
    acc[4] += xv * w1v.x; acc[5] += xv * w1v.y;
    acc[6] += xv * w1v.z; acc[7] += xv * w1v.w;
  }
#pragma unroll
  for (int off = 32; off > 0; off >>= 1) {
#pragma unroll
    for (int e = 0; e < NEXP; ++e) acc[e] += __shfl_down(acc[e], off);
  }
  if (lane == 0) {
    int best = 0; float bv = acc[0];
#pragma unroll
    for (int e = 1; e < NEXP; ++e) if (acc[e] > bv) { bv = acc[e]; best = e; }
    float sum = 0.f;
#pragma unroll
    for (int e = 0; e < NEXP; ++e) sum += expf(acc[e] - bv);
    eidx[s] = best;
    gtok[s] = 1.f / sum;   // exp(best - max) == 1
  }
}

// ---------------- ordered slot assignment (cumsum semantics) ----------------
__global__ __launch_bounds__(512) void moe_scan(const int* __restrict__ eidx,
                                                const float* __restrict__ gtok,
                                                int* __restrict__ s2t,
                                                float* __restrict__ rgate) {
  const int tid = threadIdx.x;
  for (int i = tid; i < NEXP * CAP; i += 512) { s2t[i] = -1; rgate[i] = 0.f; }
  __syncthreads();
  const int w = tid >> 6, lane = tid & 63;
  const unsigned long long below = (1ull << lane) - 1ull;
  int count = 0;
  int e_next = eidx[lane];
  float g_next = gtok[lane];
  for (int base = 0; base < S_TOK; base += 64) {
    int e = e_next; float g = g_next;
    if (base + 64 < S_TOK) { e_next = eidx[base + 64 + lane]; g_next = gtok[base + 64 + lane]; }
    unsigned long long mask = __ballot(e == w);
    if (e == w) {
      int slot = count + __popcll(mask & below);
      if (slot < CAP) { s2t[w * CAP + slot] = base + lane; rgate[w * CAP + slot] = g; }
    }
    count += __popcll(mask);
  }
}

// ---------------- dispatch: gather kept tokens, fp32 -> fp16 ----------------
__global__ __launch_bounds__(128) void moe_dispatch(const float* __restrict__ x,
                                                    const int* __restrict__ s2t,
                                                    _Float16* __restrict__ disp) {
  const int row = blockIdx.x;
  const int t = threadIdx.x;
  const int token = s2t[row];
  half8 v;
  if (token >= 0) {
    const float4* xr = (const float4*)(x + (size_t)token * DDIM);
    float4 a = xr[2 * t], b = xr[2 * t + 1];
    v[0] = (_Float16)a.x; v[1] = (_Float16)a.y; v[2] = (_Float16)a.z; v[3] = (_Float16)a.w;
    v[4] = (_Float16)b.x; v[5] = (_Float16)b.y; v[6] = (_Float16)b.z; v[7] = (_Float16)b.w;
  } else {
#pragma unroll
    for (int i = 0; i < 8; ++i) v[i] = (_Float16)0.f;
  }
  *(half8*)(disp + (size_t)row * DDIM + t * 8) = v;
}

// ---------------- transpose + fp32->fp16 convert: in[R][Cc] -> out[Cc][R] ----------------
__global__ __launch_bounds__(256) void transpose_cvt(const float* __restrict__ in,
                                                     _Float16* __restrict__ out,
                                                     int R, int Cc) {
  __shared__ float tile[64][65];
  const size_t mat = (size_t)R * Cc;
  const float* ip = in + (size_t)blockIdx.z * mat;
  _Float16* op = out + (size_t)blockIdx.z * mat;
  const int r0 = blockIdx.y * 64, c0 = blockIdx.x * 64;
  const int tx = threadIdx.x & 63, ty = threadIdx.x >> 6;
#pragma unroll
  for (int i = 0; i < 16; ++i) {
    int rl = ty * 16 + i;
    tile[rl][tx] = ip[(size_t)(r0 + rl) * Cc + c0 + tx];
  }
  __syncthreads();
  const int tx2 = threadIdx.x & 31, ty2 = threadIdx.x >> 5;
#pragma unroll
  for (int i = 0; i < 8; ++i) {
    int cl = ty2 * 8 + i;
    int rl = tx2 * 2;
    half2v v;
    v[0] = (_Float16)tile[rl][cl];
    v[1] = (_Float16)tile[rl + 1][cl];
    *(half2v*)(op + (size_t)(c0 + cl) * R + r0 + rl) = v;
  }
}

// ---------------- grouped GEMM: out = A[z] @ B[z]^T (B stored [N][K]) ----------------
// FIRST: out = relu -> fp16 Hout.  !FIRST: scatter (atomicAdd if SPLITK>1) to Y.
// 1D grid, XCD-chunked (xcd == expert) + 2x2 supertile zigzag inside an expert.
template <int KDIM, int NDIM, bool FIRST, int SPLITK, int GX, int GY>
__global__ __launch_bounds__(256) void ffn_gemm(const _Float16* __restrict__ A_set,
                                                const _Float16* __restrict__ B_set,
                                                _Float16* __restrict__ Hout,
                                                float* __restrict__ Y,
                                                const int* __restrict__ s2t,
                                                const float* __restrict__ rgate) {
  __shared__ _Float16 As[128 * 32];
  __shared__ _Float16 Bs[128 * 32];
  constexpr int PER_E = GX * GY * SPLITK;
  constexpr int CPX = PER_E * NEXP / 8;       // blocks per XCD
  const int wg = blockIdx.x;
  const int swz = (wg & 7) * CPX + (wg >> 3); // bijective: xcd = wg & 7
  const int z = swz / PER_E;                  // expert (== xcd here)
  const int srem = swz % PER_E;
  const int ks = srem / (GX * GY);            // K-split segment
  const int s2 = srem % (GX * GY);
  constexpr int SX = GX / 2;
  const int st = s2 >> 2;
  const int x = (st % SX) * 2 + (s2 & 1);
  const int yb = (st / SX) * 2 + ((s2 >> 1) & 1);

  const int m0 = yb * 128;
  const int n0 = x * 128;
  const int tid = threadIdx.x;
  const int lane = tid & 63;
  const int wr = tid >> 7;          // wave row (0..1)
  const int wc = (tid >> 6) & 1;    // wave col (0..1)

  const _Float16* Ae = A_set + (size_t)z * 1024 * KDIM;
  const _Float16* Be = B_set + (size_t)z * (size_t)NDIM * KDIM;

  const int row_a = tid >> 2;                          // staging row 0..63
  const int kp = (((tid & 3) ^ ((tid >> 3) & 3)) << 3); // swizzled k sub-offset

  f32x4 acc[4][4];
#pragma unroll
  for (int m = 0; m < 4; ++m)
#pragma unroll
    for (int n = 0; n < 4; ++n) acc[m][n] = {0.f, 0.f, 0.f, 0.f};

  constexpr int KSEG = KDIM / SPLITK;
  const int kbeg = ks * KSEG;
  for (int k0 = kbeg; k0 < kbeg + KSEG; k0 += 32) {
    __syncthreads();
    load_lds16(Ae + (size_t)(m0 + row_a) * KDIM + k0 + kp, As + tid * 8);
    load_lds16(Ae + (size_t)(m0 + 64 + row_a) * KDIM + k0 + kp, As + 2048 + tid * 8);
    load_lds16(Be + (size_t)(n0 + row_a) * KDIM + k0 + kp, Bs + tid * 8);
    load_lds16(Be + (size_t)(n0 + 64 + row_a) * KDIM + k0 + kp, Bs + 2048 + tid * 8);
    __syncthreads();
    half8 af[4], bf[4];
#pragma unroll
    for (int m = 0; m < 4; ++m)
      af[m] = *(const half8*)(As + lds_idx(wr * 64 + m * 16 + (lane & 15), lane >> 4));
#pragma unroll
    for (int n = 0; n < 4; ++n)
      bf[n] = *(const half8*)(Bs + lds_idx(wc * 64 + n * 16 + (lane & 15), lane >> 4));
#pragma unroll
    for (int m = 0; m < 4; ++m)
#pragma unroll
      for (int n = 0; n < 4; ++n)
        acc[m][n] = __builtin_amdgcn_mfma_f32_16x16x32_f16(af[m], bf[n], acc[m][n], 0, 0, 0);
  }

  const int rbase = wr * 64 + (lane >> 4) * 4;   // + m*16 + j
  const int cbase = n0 + wc * 64 + (lane & 15);  // + n*16
  if (FIRST) {
#pragma unroll
    for (int m = 0; m < 4; ++m) {
      int row = m0 + rbase + m * 16;
#pragma unroll
      for (int n = 0; n < 4; ++n) {
        int col = cbase + n * 16;
#pragma unroll
        for (int j = 0; j < 4; ++j) {
          float v = fmaxf(acc[m][n][j], 0.f);
          Hout[((size_t)z * 1024 + row + j) * NDIM + col] = (_Float16)v;
        }
      }
    }
  } else {
#pragma unroll
    for (int m = 0; m < 4; ++m) {
      int srow = z * CAP + m0 + rbase + m * 16;
#pragma unroll
      for (int j = 0; j < 4; ++j) {
        int token = s2t[srow + j];
        if (token < 0) continue;
        float g = rgate[srow + j];
#pragma unroll
        for (int n = 0; n < 4; ++n) {
          int col = cbase + n * 16;
          if (SPLITK > 1)
            atomicAdd(&Y[(size_t)token * DDIM + col], acc[m][n][j] * g);
          else
            Y[(size_t)token * DDIM + col] = acc[m][n][j] * g;
        }
      }
    }
  }
}

extern "C" void kernel_launch(void* const* d_in, const int* in_sizes, int n_in,
                              void* d_out, int out_size, void* d_ws, size_t ws_size,
                              hipStream_t stream) {
  const float* x  = (const float*)d_in[0];
  const float* wg = (const float*)d_in[1];
  const float* w1 = (const float*)d_in[2];
  const float* w2 = (const float*)d_in[3];
  float* y = (float*)d_out;

  char* ws = (char*)d_ws;
  int*   eidx  = (int*)(ws);
  float* gtok  = (float*)(ws + 32768);
  int*   s2t   = (int*)(ws + 65536);
  float* rgate = (float*)(ws + 98304);
  _Float16* disp = (_Float16*)(ws + 131072);
  char* big = ws + 131072 + (size_t)NEXP * CAP * DDIM * 2;  // after disp (16 MB)
  _Float16* hbuf = (_Float16*)big;                  // [E][C][H] fp16, 67 MB
  _Float16* wt   = (_Float16*)(big + 67108864);     // shared w1t then w2t, 67 MB

  moe_gating<<<S_TOK / 4, 256, 0, stream>>>(x, wg, eidx, gtok);
  moe_scan<<<1, 512, 0, stream>>>(eidx, gtok, s2t, rgate);
  moe_dispatch<<<NEXP * CAP, 128, 0, stream>>>(x, s2t, disp);
  (void)hipMemsetAsync(d_out, 0, (size_t)out_size * sizeof(float), stream);

  // GEMM1: [C,D] x [D,H] -> relu -> hbuf (fp16).  grid 32*8*8 = 2048
  transpose_cvt<<<dim3(HDIM / 64, DDIM / 64, NEXP), 256, 0, stream>>>(w1, wt, DDIM, HDIM);
  ffn_gemm<DDIM, HDIM, true, 1, 32, 8><<<2048, 256, 0, stream>>>(
      disp, wt, hbuf, nullptr, nullptr, nullptr);

  // GEMM2: [C,H] x [H,D] -> scatter to y.  split-K=2, grid 8*8*2*8 = 1024
  transpose_cvt<<<dim3(DDIM / 64, HDIM / 64, NEXP), 256, 0, stream>>>(w2, wt, HDIM, DDIM);
  ffn_gemm<HDIM, DDIM, false, 2, 8, 8><<<1024, 256, 0, stream>>>(
      hbuf, wt, nullptr, y, s2t, rgate);
}

// Round 3
// 361.477 us; speedup vs baseline: 1.0721x; 1.0721x over previous
//
#include <hip/hip_runtime.h>
#include <hip/hip_fp16.h>

#define S_TOK 8192
#define DDIM  1024
#define HDIM  4096
#define NEXP  8
#define CAP   1024

typedef __attribute__((ext_vector_type(8))) _Float16 half8;
typedef __attribute__((ext_vector_type(4))) float f32x4;

__device__ __forceinline__ void load_lds16(const _Float16* g, _Float16* l) {
  __builtin_amdgcn_global_load_lds(
      (const __attribute__((address_space(1))) unsigned int*)g,
      (__attribute__((address_space(3))) unsigned int*)l, 16, 0, 0);
}

// LDS fragment address with the same XOR swizzle used on the staging source.
// Half-tile stored as [64 rows][32 halfs]; 16B chunk col c of row r holds
// global k-chunk (c ^ ((r>>1)&3)).
__device__ __forceinline__ int lds_idx(int r, int kslot) {
  return (r & 63) * 32 + (r >> 6) * 2048 + ((kslot ^ ((r >> 1) & 3)) << 3);
}

// ---------------- gating: logits = x @ wg, softmax, top-1 ----------------
__global__ __launch_bounds__(256) void moe_gating(const float* __restrict__ x,
                                                  const float* __restrict__ wg,
                                                  int* __restrict__ eidx,
                                                  float* __restrict__ gtok) {
  const int s = blockIdx.x * 4 + (threadIdx.x >> 6);
  const int lane = threadIdx.x & 63;
  const float* xr = x + (size_t)s * DDIM;
  float acc[NEXP];
#pragma unroll
  for (int e = 0; e < NEXP; ++e) acc[e] = 0.f;
  for (int d = lane; d < DDIM; d += 64) {
    float xv = xr[d];
    const float4* wrow = (const float4*)(wg + (size_t)d * NEXP);
    float4 w0 = wrow[0], w1v = wrow[1];
    acc[0] += xv * w0.x;  acc[1] += xv * w0.y;
    acc[2] += xv * w0.z;  acc[3] += xv * w0.w;
    acc[4] += xv * w1v.x; acc[5] += xv * w1v.y;
    acc[6] += xv * w1v.z; acc[7] += xv * w1v.w;
  }
#pragma unroll
  for (int off = 32; off > 0; off >>= 1) {
#pragma unroll
    for (int e = 0; e < NEXP; ++e) acc[e] += __shfl_down(acc[e], off);
  }
  if (lane == 0) {
    int best = 0; float bv = acc[0];
#pragma unroll
    for (int e = 1; e < NEXP; ++e) if (acc[e] > bv) { bv = acc[e]; best = e; }
    float sum = 0.f;
#pragma unroll
    for (int e = 0; e < NEXP; ++e) sum += expf(acc[e] - bv);
    eidx[s] = best;
    gtok[s] = 1.f / sum;   // exp(best - max) == 1
  }
}

// ---------------- ordered slot assignment (cumsum semantics) ----------------
__global__ __launch_bounds__(512) void moe_scan(const int* __restrict__ eidx,
                                                const float* __restrict__ gtok,
                                                int* __restrict__ s2t,
                                                float* __restrict__ rgate) {
  const int tid = threadIdx.x;
  for (int i = tid; i < NEXP * CAP; i += 512) { s2t[i] = -1; rgate[i] = 0.f; }
  __syncthreads();
  const int w = tid >> 6, lane = tid & 63;
  const unsigned long long below = (1ull << lane) - 1ull;
  int count = 0;
  int e_next = eidx[lane];
  float g_next = gtok[lane];
  for (int base = 0; base < S_TOK; base += 64) {
    int e = e_next; float g = g_next;
    if (base + 64 < S_TOK) { e_next = eidx[base + 64 + lane]; g_next = gtok[base + 64 + lane]; }
    unsigned long long mask = __ballot(e == w);
    if (e == w) {
      int slot = count + __popcll(mask & below);
      if (slot < CAP) { s2t[w * CAP + slot] = base + lane; rgate[w * CAP + slot] = g; }
    }
    count += __popcll(mask);
  }
}

// ---------------- dispatch: gather kept tokens, fp32 -> fp16 ----------------
__global__ __launch_bounds__(128) void moe_dispatch(const float* __restrict__ x,
                                                    const int* __restrict__ s2t,
                                                    _Float16* __restrict__ disp) {
  const int row = blockIdx.x;
  const int t = threadIdx.x;
  const int token = s2t[row];
  half8 v;
  if (token >= 0) {
    const float4* xr = (const float4*)(x + (size_t)token * DDIM);
    float4 a = xr[2 * t], b = xr[2 * t + 1];
    v[0] = (_Float16)a.x; v[1] = (_Float16)a.y; v[2] = (_Float16)a.z; v[3] = (_Float16)a.w;
    v[4] = (_Float16)b.x; v[5] = (_Float16)b.y; v[6] = (_Float16)b.z; v[7] = (_Float16)b.w;
  } else {
#pragma unroll
    for (int i = 0; i < 8; ++i) v[i] = (_Float16)0.f;
  }
  *(half8*)(disp + (size_t)row * DDIM + t * 8) = v;
}

// ---------------- transpose + fp32->fp16 convert: in[R][Cc] -> out[Cc][R] ----------------
__global__ __launch_bounds__(256) void transpose_cvt(const float* __restrict__ in,
                                                     _Float16* __restrict__ out,
                                                     int R, int Cc) {
  __shared__ float tile[64][65];
  const size_t mat = (size_t)R * Cc;
  const float* ip = in + (size_t)blockIdx.z * mat;
  _Float16* op = out + (size_t)blockIdx.z * mat;
  const int r0 = blockIdx.y * 64, c0 = blockIdx.x * 64;
  const int tx = threadIdx.x & 63, ty = threadIdx.x >> 6;
#pragma unroll
  for (int i = 0; i < 16; ++i) {
    int rl = ty * 16 + i;
    tile[rl][tx] = ip[(size_t)(r0 + rl) * Cc + c0 + tx];
  }
  __syncthreads();
  // store side: 16B per lane, lanes cover contiguous r within a column
  const int cl = threadIdx.x >> 3;        // 0..31
  const int rch = (threadIdx.x & 7) * 8;  // row chunk base
#pragma unroll
  for (int pass = 0; pass < 2; ++pass) {
    int cc = cl + pass * 32;
    half8 v;
#pragma unroll
    for (int i = 0; i < 8; ++i) v[i] = (_Float16)tile[rch + i][cc];
    *(half8*)(op + (size_t)(c0 + cc) * R + r0 + rch) = v;
  }
}

// ---------------- grouped GEMM: out = A[z] @ B[z]^T (B stored [N][K]) ----------------
// Double-buffered LDS, prefetch-before-compute (minimum-2-phase, T3 recipe).
// FIRST: out = relu -> fp16 Hout.  !FIRST: scatter fp32 to Y via slot2token * gate.
// 1D grid, XCD-chunked (xcd == expert) + 2x2 supertile zigzag inside an expert.
template <int KDIM, int NDIM, bool FIRST, int GX, int GY>
__global__ __launch_bounds__(256) void ffn_gemm(const _Float16* __restrict__ A_set,
                                                const _Float16* __restrict__ B_set,
                                                _Float16* __restrict__ Hout,
                                                float* __restrict__ Y,
                                                const int* __restrict__ s2t,
                                                const float* __restrict__ rgate) {
  __shared__ _Float16 As[2 * 128 * 32];
  __shared__ _Float16 Bs[2 * 128 * 32];
  constexpr int PER_E = GX * GY;
  constexpr int CPX = PER_E * NEXP / 8;       // blocks per XCD
  const int wg = blockIdx.x;
  const int swz = (wg & 7) * CPX + (wg >> 3); // bijective: xcd = wg & 7
  const int z = swz / PER_E;                  // expert (== xcd here)
  const int s2 = swz % PER_E;
  constexpr int SX = GX / 2;
  const int st = s2 >> 2;
  const int x = (st % SX) * 2 + (s2 & 1);
  const int yb = (st / SX) * 2 + ((s2 >> 1) & 1);

  const int m0 = yb * 128;
  const int n0 = x * 128;
  const int tid = threadIdx.x;
  const int lane = tid & 63;
  const int wr = tid >> 7;          // wave row (0..1)
  const int wc = (tid >> 6) & 1;    // wave col (0..1)

  const _Float16* Ae = A_set + (size_t)z * 1024 * KDIM;
  const _Float16* Be = B_set + (size_t)z * (size_t)NDIM * KDIM;

  const int row_a = tid >> 2;                           // staging row 0..63
  const int kp = (((tid & 3) ^ ((tid >> 3) & 3)) << 3); // swizzled k sub-offset

  f32x4 acc[4][4];
#pragma unroll
  for (int m = 0; m < 4; ++m)
#pragma unroll
    for (int n = 0; n < 4; ++n) acc[m][n] = {0.f, 0.f, 0.f, 0.f};

  auto STAGE = [&](int buf, int k0) {
    _Float16* Ab = As + buf * 4096;
    _Float16* Bb = Bs + buf * 4096;
    load_lds16(Ae + (size_t)(m0 + row_a) * KDIM + k0 + kp, Ab + tid * 8);
    load_lds16(Ae + (size_t)(m0 + 64 + row_a) * KDIM + k0 + kp, Ab + 2048 + tid * 8);
    load_lds16(Be + (size_t)(n0 + row_a) * KDIM + k0 + kp, Bb + tid * 8);
    load_lds16(Be + (size_t)(n0 + 64 + row_a) * KDIM + k0 + kp, Bb + 2048 + tid * 8);
  };
  auto COMPUTE = [&](int buf) {
    const _Float16* Ab = As + buf * 4096;
    const _Float16* Bb = Bs + buf * 4096;
    half8 af[4], bf[4];
#pragma unroll
    for (int m = 0; m < 4; ++m)
      af[m] = *(const half8*)(Ab + lds_idx(wr * 64 + m * 16 + (lane & 15), lane >> 4));
#pragma unroll
    for (int n = 0; n < 4; ++n)
      bf[n] = *(const half8*)(Bb + lds_idx(wc * 64 + n * 16 + (lane & 15), lane >> 4));
    __builtin_amdgcn_s_setprio(1);
#pragma unroll
    for (int m = 0; m < 4; ++m)
#pragma unroll
      for (int n = 0; n < 4; ++n)
        acc[m][n] = __builtin_amdgcn_mfma_f32_16x16x32_f16(af[m], bf[n], acc[m][n], 0, 0, 0);
    __builtin_amdgcn_s_setprio(0);
  };

  // prologue: stage tile 0, single drain
  STAGE(0, 0);
  __syncthreads();
  int cur = 0;
  // steady state: issue next-tile stage BEFORE computing current tile;
  // one barrier per K-step (compiler emits vmcnt(0)+lgkmcnt(0) at it).
  for (int k0 = 32; k0 < KDIM; k0 += 32) {
    STAGE(cur ^ 1, k0);
    COMPUTE(cur);
    __syncthreads();
    cur ^= 1;
  }
  COMPUTE(cur);   // epilogue tile (no prefetch)

  const int rbase = wr * 64 + (lane >> 4) * 4;   // + m*16 + j
  const int cbase = n0 + wc * 64 + (lane & 15);  // + n*16
  if (FIRST) {
#pragma unroll
    for (int m = 0; m < 4; ++m) {
      int row = m0 + rbase + m * 16;
#pragma unroll
      for (int n = 0; n < 4; ++n) {
        int col = cbase + n * 16;
#pragma unroll
        for (int j = 0; j < 4; ++j) {
          float v = fmaxf(acc[m][n][j], 0.f);
          Hout[((size_t)z * 1024 + row + j) * NDIM + col] = (_Float16)v;
        }
      }
    }
  } else {
#pragma unroll
    for (int m = 0; m < 4; ++m) {
      int srow = z * CAP + m0 + rbase + m * 16;
#pragma unroll
      for (int j = 0; j < 4; ++j) {
        int token = s2t[srow + j];
        if (token < 0) continue;
        float g = rgate[srow + j];
#pragma unroll
        for (int n = 0; n < 4; ++n) {
          int col = cbase + n * 16;
          Y[(size_t)token * DDIM + col] = acc[m][n][j] * g;
        }
      }
    }
  }
}

extern "C" void kernel_launch(void* const* d_in, const int* in_sizes, int n_in,
                              void* d_out, int out_size, void* d_ws, size_t ws_size,
                              hipStream_t stream) {
  const float* x  = (const float*)d_in[0];
  const float* wg = (const float*)d_in[1];
  const float* w1 = (const float*)d_in[2];
  const float* w2 = (const float*)d_in[3];
  float* y = (float*)d_out;

  char* ws = (char*)d_ws;
  int*   eidx  = (int*)(ws);
  float* gtok  = (float*)(ws + 32768);
  int*   s2t   = (int*)(ws + 65536);
  float* rgate = (float*)(ws + 98304);
  _Float16* disp = (_Float16*)(ws + 131072);
  char* big = ws + 131072 + (size_t)NEXP * CAP * DDIM * 2;  // after disp (16 MB)
  _Float16* hbuf = (_Float16*)big;                  // [E][C][H] fp16, 67 MB
  _Float16* wt   = (_Float16*)(big + 67108864);     // shared w1t then w2t, 67 MB

  moe_gating<<<S_TOK / 4, 256, 0, stream>>>(x, wg, eidx, gtok);
  moe_scan<<<1, 512, 0, stream>>>(eidx, gtok, s2t, rgate);
  moe_dispatch<<<NEXP * CAP, 128, 0, stream>>>(x, s2t, disp);
  (void)hipMemsetAsync(d_out, 0, (size_t)out_size * sizeof(float), stream);

  // GEMM1: [C,D] x [D,H] -> relu -> hbuf (fp16).  grid 32*8*8 = 2048
  transpose_cvt<<<dim3(HDIM / 64, DDIM / 64, NEXP), 256, 0, stream>>>(w1, wt, DDIM, HDIM);
  ffn_gemm<DDIM, HDIM, true, 32, 8><<<2048, 256, 0, stream>>>(
      disp, wt, hbuf, nullptr, nullptr, nullptr);

  // GEMM2: [C,H] x [H,D] -> scatter to y.  grid 8*8*8 = 512
  transpose_cvt<<<dim3(DDIM / 64, HDIM / 64, NEXP), 256, 0, stream>>>(w2, wt, HDIM, DDIM);
  ffn_gemm<HDIM, DDIM, false, 8, 8><<<512, 256, 0, stream>>>(
      hbuf, wt, nullptr, y, s2t, rgate);
}